// Round 1
// baseline (1438.608 us; speedup 1.0000x reference)
//
#include <hip/hip_runtime.h>

#define HW 65536
#define IMG 256

__device__ __forceinline__ float hsum4(float4 v) { return v.x + v.y + v.z + v.w; }
__device__ __forceinline__ float lrelu(float v) { return v >= 0.f ? v : 0.2f * v; }

// ---------------- 1x1 conv, latency-optimized ----------------
// v4: explicit 4-deep prefetch ring (static indexing) so VMEM issue is continuous,
// COPW=8 channels/wave + co-split over blockIdx.z + launch_bounds(256,8) for 8 waves/SIMD.
// COPW=16 path (z=1) kept for the in-place final conv (block reads all ch before writing).
// stats != null (and !GNIN): fused GroupNorm partial sum/sumsq of raw outputs via atomics.
// GNIN: apply per-input-channel GN affine + leaky-relu while reading (single group).
template<int CIT, int COPW, bool GNIN>
__global__ __launch_bounds__(256, (COPW == 8) ? 8 : 4)
void conv1x1_v4(const float* __restrict__ in, int in_cs,
                const float* __restrict__ w, int w_bstride,
                const float* __restrict__ bias,
                float* __restrict__ out, int out_cs, int out_coff,
                float* __restrict__ stats, int gsel,
                const float* __restrict__ gstats,
                const float* __restrict__ g_gamma, const float* __restrict__ g_beta,
                int g_coff, float g_Nf)
{
    const int b  = blockIdx.y;
    const int j  = threadIdx.x & 63;
    const int wv = __builtin_amdgcn_readfirstlane((int)(threadIdx.x >> 6));
    const int co0 = ((int)blockIdx.z * 4 + wv) * COPW;
    const int q0 = blockIdx.x * 64;
    const float4* in4 = (const float4*)in + (size_t)b * in_cs * (HW/4) + q0 + j;
    const float* wb = w + (size_t)b * w_bstride;

    float gmean = 0.f, grstd = 0.f;
    if (GNIN) {
        gmean = gstats[b*4] / g_Nf;
        float var = gstats[b*4 + 1] / g_Nf - gmean * gmean;
        grstd = rsqrtf(var + 1e-5f);
    }

    float4 acc[COPW];
    #pragma unroll
    for (int k = 0; k < COPW; ++k) {
        float bv = bias ? bias[co0 + k] : 0.f;
        acc[k] = make_float4(bv, bv, bv, bv);
    }

    auto fmabody = [&](int ci, float4 x) {
        if (GNIN) {
            float A = g_gamma[g_coff + ci] * grstd;
            float B = g_beta[g_coff + ci] - gmean * A;
            x.x = lrelu(fmaf(x.x, A, B));
            x.y = lrelu(fmaf(x.y, A, B));
            x.z = lrelu(fmaf(x.z, A, B));
            x.w = lrelu(fmaf(x.w, A, B));
        }
        const float* wr = wb + ci;
        #pragma unroll
        for (int k = 0; k < COPW; ++k) {
            float wk = wr[(size_t)(co0 + k) * CIT];
            acc[k].x = fmaf(wk, x.x, acc[k].x);
            acc[k].y = fmaf(wk, x.y, acc[k].y);
            acc[k].z = fmaf(wk, x.z, acc[k].z);
            acc[k].w = fmaf(wk, x.w, acc[k].w);
        }
    };

    // 4-deep prefetch ring, statically indexed (stays in registers)
    float4 xb[4];
    #pragma unroll
    for (int p = 0; p < 4; ++p) xb[p] = in4[(size_t)p * (HW/4)];

    for (int cg = 0; cg < CIT/4 - 1; ++cg) {
        #pragma unroll
        for (int u = 0; u < 4; ++u) {
            const int ci = cg*4 + u;
            float4 x = xb[u];
            xb[u] = in4[(size_t)(ci + 4) * (HW/4)];   // issue next-group load before FMAs
            fmabody(ci, x);
        }
    }
    #pragma unroll
    for (int u = 0; u < 4; ++u) fmabody(CIT - 4 + u, xb[u]);

    if (!GNIN && stats) {
        float s = 0.f, ss = 0.f;
        #pragma unroll
        for (int k = 0; k < COPW; ++k) {
            s  += acc[k].x + acc[k].y + acc[k].z + acc[k].w;
            ss += acc[k].x*acc[k].x + acc[k].y*acc[k].y
                + acc[k].z*acc[k].z + acc[k].w*acc[k].w;
        }
        #pragma unroll
        for (int o = 32; o; o >>= 1) { s += __shfl_down(s, o, 64); ss += __shfl_down(ss, o, 64); }
        if (j == 0) {
            const int g = (gsel < 0) ? (co0 >= 32 ? 1 : 0) : 0;
            float* st = stats + (size_t)b*4 + g*2;
            atomicAdd(st,     s);
            atomicAdd(st + 1, ss);
        }
    }

    if (GNIN) __syncthreads();   // in-place safety: all global reads of this block precede any write

    float4* out4 = (float4*)out + ((size_t)b * out_cs + out_coff) * (HW/4) + q0 + j;
    #pragma unroll
    for (int k = 0; k < COPW; ++k)
        out4[(size_t)(co0 + k) * (HW/4)] = acc[k];
}

// ---------------- depthwise conv (5x5 pad2 / 3x3 dil3 pad3), 64 channels per dispatch ----------------
// grid: (4, 16, nb*64), block 256; thread computes 4 px of one row.
template<int TAPS, int DIL>
__global__ __launch_bounds__(256)
void dwconv_v2(const float* __restrict__ in, int in_cs, int in_coff,
               const float* __restrict__ wt, const float* __restrict__ bias, int w_coff,
               float* __restrict__ out, int out_cs, int out_coff)
{
    constexpr int HALO = DIL * (TAPS/2);
    constexpr int TW = 64, TH = 16;
    constexpr int LW = TW + 2*HALO;
    constexpr int LH = TH + 2*HALO;
    constexpr int RS = (LW + 3) & ~3;
    __shared__ float Xs[LH * RS];
    const int z = blockIdx.z;
    const int c = z & 63, b = z >> 6;
    const int x0 = blockIdx.x * TW, y0 = blockIdx.y * TH;
    const float* ip = in + ((size_t)b*in_cs + in_coff + c) * HW;
    const int cw = w_coff + c;
    float wk[TAPS*TAPS];
    #pragma unroll
    for (int i = 0; i < TAPS*TAPS; ++i) wk[i] = wt[cw*TAPS*TAPS + i];
    const float bv = bias[cw];
    for (int idx = threadIdx.x; idx < LH*LW; idx += 256) {
        int ly = idx / LW, lx = idx - ly*LW;
        int gy = y0 + ly - HALO, gx = x0 + lx - HALO;
        float v = 0.f;
        if (gy >= 0 && gy < IMG && gx >= 0 && gx < IMG)
            v = ip[gy*IMG + gx];
        Xs[ly*RS + lx] = v;
    }
    __syncthreads();
    const int qx = (threadIdx.x & 15) * 4;
    const int ly = threadIdx.x >> 4;
    float o0 = bv, o1 = bv, o2 = bv, o3 = bv;
    #pragma unroll
    for (int ky = 0; ky < TAPS; ++ky) {
        const float* row = &Xs[(ly + ky*DIL)*RS + qx];
        float win[(TAPS-1)*DIL + 4];
        #pragma unroll
        for (int i = 0; i < (TAPS-1)*DIL + 4; ++i) win[i] = row[i];
        #pragma unroll
        for (int kx = 0; kx < TAPS; ++kx) {
            float wv_ = wk[ky*TAPS + kx];
            o0 = fmaf(wv_, win[kx*DIL + 0], o0);
            o1 = fmaf(wv_, win[kx*DIL + 1], o1);
            o2 = fmaf(wv_, win[kx*DIL + 2], o2);
            o3 = fmaf(wv_, win[kx*DIL + 3], o3);
        }
    }
    *(float4*)(out + ((size_t)b*out_cs + out_coff + c) * HW + (size_t)(y0 + ly)*IMG + x0 + qx) =
        make_float4(o0, o1, o2, o3);
}

// ---------------- attention raw dots, with GN+leaky fused on q,k + post-act sumsq ----------------
// grid: (128, 4, nb), block 256. LDS transposed [t][c] for conflict-free b128 reads.
__global__ __launch_bounds__(256)
void attn_dot_v3(const float* __restrict__ q, const float* __restrict__ k,
                 const float* __restrict__ stQ, const float* __restrict__ stK,
                 const float* __restrict__ qg, const float* __restrict__ qb,
                 const float* __restrict__ kg, const float* __restrict__ kb,
                 float* __restrict__ attn_raw,
                 float* __restrict__ ssq, float* __restrict__ ssk)
{
    __shared__ float4 qs[2048], ks[2048];   // 32 KiB each
    __shared__ float sred[512];
    const int h = blockIdx.y, b = blockIdx.z;
    const int t0 = blockIdx.x * 128;
    const int cc = threadIdx.x & 15;
    const int ch = h*16 + cc;               // channel index within the 64-ch tensor

    // q GN params: 64 ch in 2 groups of 32
    const int gq = (ch >= 32) ? 1 : 0;
    float mq = stQ[b*4 + gq*2] / (32.f * HW);
    float vq = stQ[b*4 + gq*2 + 1] / (32.f * HW) - mq*mq;
    const float Aq = qg[ch] * rsqrtf(vq + 1e-5f);
    const float Bq = qb[ch] - mq * Aq;
    // k channels are kv-c1 channels 0..63 -> all in kv group 0 (of 64 ch)
    float mk = stK[b*4] / (64.f * HW);
    float vk = stK[b*4 + 1] / (64.f * HW) - mk*mk;
    const float Ak = kg[ch] * rsqrtf(vk + 1e-5f);
    const float Bk = kb[ch] - mk * Ak;

    const float4* q4 = (const float4*)q + ((size_t)b*64 + ch) * (HW/4) + t0;
    const float4* k4 = (const float4*)k + ((size_t)b*64 + ch) * (HW/4) + t0;
    float sq_acc = 0.f, sk_acc = 0.f;
    #pragma unroll
    for (int s = 0; s < 8; ++s) {
        int t = (threadIdx.x >> 4) + s*16;
        float4 v = q4[t];
        v.x = lrelu(fmaf(v.x, Aq, Bq)); v.y = lrelu(fmaf(v.y, Aq, Bq));
        v.z = lrelu(fmaf(v.z, Aq, Bq)); v.w = lrelu(fmaf(v.w, Aq, Bq));
        sq_acc += v.x*v.x + v.y*v.y + v.z*v.z + v.w*v.w;
        qs[t*16 + cc] = v;
        float4 u = k4[t];
        u.x = lrelu(fmaf(u.x, Ak, Bk)); u.y = lrelu(fmaf(u.y, Ak, Bk));
        u.z = lrelu(fmaf(u.z, Ak, Bk)); u.w = lrelu(fmaf(u.w, Ak, Bk));
        sk_acc += u.x*u.x + u.y*u.y + u.z*u.z + u.w*u.w;
        ks[t*16 + cc] = u;
    }
    sred[threadIdx.x]       = sq_acc;
    sred[256 + threadIdx.x] = sk_acc;
    __syncthreads();

    const int p   = threadIdx.x & 63;
    const int sub = threadIdx.x >> 6;
    const int c0 = (p >> 3) << 1, d0 = (p & 7) << 1;
    float4 a00 = make_float4(0,0,0,0), a01 = a00, a10 = a00, a11 = a00;
    #pragma unroll
    for (int i = 0; i < 32; ++i) {
        int t = sub*32 + i;
        float4 qa = qs[t*16 + c0], qb_ = qs[t*16 + c0 + 1];
        float4 ka = ks[t*16 + d0], kb_ = ks[t*16 + d0 + 1];
        a00.x = fmaf(qa.x, ka.x, a00.x); a00.y = fmaf(qa.y, ka.y, a00.y);
        a00.z = fmaf(qa.z, ka.z, a00.z); a00.w = fmaf(qa.w, ka.w, a00.w);
        a01.x = fmaf(qa.x, kb_.x, a01.x); a01.y = fmaf(qa.y, kb_.y, a01.y);
        a01.z = fmaf(qa.z, kb_.z, a01.z); a01.w = fmaf(qa.w, kb_.w, a01.w);
        a10.x = fmaf(qb_.x, ka.x, a10.x); a10.y = fmaf(qb_.y, ka.y, a10.y);
        a10.z = fmaf(qb_.z, ka.z, a10.z); a10.w = fmaf(qb_.w, ka.w, a10.w);
        a11.x = fmaf(qb_.x, kb_.x, a11.x); a11.y = fmaf(qb_.y, kb_.y, a11.y);
        a11.z = fmaf(qb_.z, kb_.z, a11.z); a11.w = fmaf(qb_.w, kb_.w, a11.w);
    }
    float* ar = attn_raw + ((size_t)b*4 + h) * 256;
    atomicAdd(&ar[(c0  )*16 + d0  ], hsum4(a00));
    atomicAdd(&ar[(c0  )*16 + d0+1], hsum4(a01));
    atomicAdd(&ar[(c0+1)*16 + d0  ], hsum4(a10));
    atomicAdd(&ar[(c0+1)*16 + d0+1], hsum4(a11));

    // per-channel post-activation sumsq partials
    if (threadIdx.x < 16) {
        float s = 0.f;
        #pragma unroll
        for (int jj = 0; jj < 16; ++jj) s += sred[threadIdx.x + 16*jj];
        atomicAdd(&ssq[b*64 + h*16 + threadIdx.x], s);
    } else if (threadIdx.x < 32) {
        const int c2 = threadIdx.x - 16;
        float s = 0.f;
        #pragma unroll
        for (int jj = 0; jj < 16; ++jj) s += sred[256 + c2 + 16*jj];
        atomicAdd(&ssk[b*64 + h*16 + c2], s);
    }
}

// ---------------- softmax with l2-norm scaling + temperature ----------------
// grid: (4, nb), block 256 = 16x16.
__global__ __launch_bounds__(256)
void attn_softmax_v2(const float* __restrict__ attn_raw,
                     const float* __restrict__ ssq, const float* __restrict__ ssk,
                     const float* __restrict__ temp, float* __restrict__ attn)
{
    const int h = blockIdx.x, b = blockIdx.y;
    const int c = threadIdx.x >> 4, d = threadIdx.x & 15;
    const float nq = fmaxf(sqrtf(ssq[b*64 + h*16 + c]), 1e-12f);
    const float nk = fmaxf(sqrtf(ssk[b*64 + h*16 + d]), 1e-12f);
    float logit = attn_raw[((size_t)b*4 + h)*256 + c*16 + d] / (nq * nk) * temp[h];
    float m = logit;
    #pragma unroll
    for (int o = 8; o; o >>= 1) m = fmaxf(m, __shfl_xor(m, o, 16));
    float e = expf(logit - m);
    float s = e;
    #pragma unroll
    for (int o = 8; o; o >>= 1) s += __shfl_xor(s, o, 16);
    attn[((size_t)b*4 + h)*256 + c*16 + d] = e / s;
}

// ---------------- M[b] = proj . blockdiag(attn[b]) ----------------
// grid: nb, block 256.
__global__ __launch_bounds__(256)
void build_m_v2(const float* __restrict__ attn, const float* __restrict__ proj_w,
                float* __restrict__ M)
{
    const int b = blockIdx.x;
    for (int i = threadIdx.x; i < 4096; i += 256) {
        int co = i >> 6, ci = i & 63;
        int h = ci >> 4, d = ci & 15;
        float s = 0.f;
        #pragma unroll
        for (int cc = 0; cc < 16; ++cc)
            s += proj_w[co*64 + h*16 + cc] * attn[((size_t)b*4 + h)*256 + cc*16 + d];
        M[(size_t)b*4096 + i] = s;
    }
}

extern "C" void kernel_launch(void* const* d_in, const int* in_sizes, int n_in,
                              void* d_out, int out_size, void* d_ws, size_t ws_size,
                              hipStream_t stream)
{
    const float* x       = (const float*)d_in[0];
    const float* y       = (const float*)d_in[1];
    const float* kv_w    = (const float*)d_in[2];
    const float* q_w     = (const float*)d_in[3];
    const float* proj_w  = (const float*)d_in[4];
    const float* kv_c0_w = (const float*)d_in[5];
    const float* kv_c0_b = (const float*)d_in[6];
    const float* kv_cs_w = (const float*)d_in[7];
    const float* kv_cs_b = (const float*)d_in[8];
    const float* kv_c1_w = (const float*)d_in[9];
    const float* kv_c1_b = (const float*)d_in[10];
    const float* kv_gn_g = (const float*)d_in[11];
    const float* kv_gn_b = (const float*)d_in[12];
    const float* q_c0_w  = (const float*)d_in[13];
    const float* q_c0_b  = (const float*)d_in[14];
    const float* q_cs_w  = (const float*)d_in[15];
    const float* q_cs_b  = (const float*)d_in[16];
    const float* q_c1_w  = (const float*)d_in[17];
    const float* q_c1_b  = (const float*)d_in[18];
    const float* q_gn_g  = (const float*)d_in[19];
    const float* q_gn_b  = (const float*)d_in[20];
    const float* temp    = (const float*)d_in[21];

    float* ws       = (float*)d_ws;
    float* statsKV  = ws;            // 4/batch  -> 16
    float* statsQ   = ws + 16;
    float* sumsq_k  = ws + 32;       // 64/batch -> 256
    float* sumsq_q  = ws + 288;
    float* attn_raw = ws + 544;      // 1024/batch -> 4096
    float* attn     = ws + 4640;
    float* Mw       = ws + 8736;     // 4096/batch -> 16384 (end 25120)
    float* big      = (float*)((char*)d_ws + 131072);

    // per-batch big-buffer need: H1 = 128*HW, H2 = 64*HW floats (48 MiB); O lives in d_out
    const size_t perb_bytes = (size_t)192 * HW * 4;
    int nb = 1;
    if      (ws_size >= 131072 + 4*perb_bytes) nb = 4;
    else if (ws_size >= 131072 + 2*perb_bytes) nb = 2;

    hipMemsetAsync(d_ws, 0, 102400, stream);
    dim3 blk(256);

    for (int b0 = 0; b0 < 4; b0 += nb) {
        const float* xb = x + (size_t)b0*64*HW;
        const float* yb = y + (size_t)b0*64*HW;
        float* H1 = big;                          // nb*128*HW
        float* H2 = big + (size_t)nb*128*HW;      // nb*64*HW
        float* O  = (float*)d_out + (size_t)b0*64*HW;   // nb*64*HW (d_out as scratch/v)
        float* Q1 = H1;
        float* Q2 = H1 + (size_t)nb*64*HW;
        float* stK = statsKV + b0*4;
        float* stQ = statsQ  + b0*4;
        float* ssk = sumsq_k + b0*64;
        float* ssq = sumsq_q + b0*64;
        float* arw = attn_raw + b0*1024;
        float* atn = attn     + b0*1024;
        float* Mb  = Mw       + b0*4096;

        dim3 gdw(4, 16, nb*64);

        // ---- kv chain: 1x1 (k-pre + v-pre merged) -> dw5x5 -> dw3x3d3 -> 1x1 c1 (raw + fused GN stats) ----
        conv1x1_v4<64,8,false><<<dim3(256,nb,4), blk, 0, stream>>>(yb, 64, kv_w, 0, nullptr, H1, 128, 0,
                                                        nullptr, 0, nullptr, nullptr, nullptr, 0, 0.f);
        dwconv_v2<5,1><<<gdw, blk, 0, stream>>>(H1, 128, 0,  kv_c0_w, kv_c0_b, 0,  H2, 64, 0);
        dwconv_v2<5,1><<<gdw, blk, 0, stream>>>(H1, 128, 64, kv_c0_w, kv_c0_b, 64, O,  64, 0);
        dwconv_v2<3,3><<<gdw, blk, 0, stream>>>(H2, 64, 0, kv_cs_w, kv_cs_b, 0,  H1, 128, 0);
        dwconv_v2<3,3><<<gdw, blk, 0, stream>>>(O,  64, 0, kv_cs_w, kv_cs_b, 64, H1, 128, 64);
        conv1x1_v4<128,8,false><<<dim3(256,nb,2), blk, 0, stream>>>(H1, 128, kv_c1_w,        0, kv_c1_b,    H2, 64, 0,
                                                         stK,   0, nullptr, nullptr, nullptr, 0, 0.f);
        conv1x1_v4<128,8,false><<<dim3(256,nb,2), blk, 0, stream>>>(H1, 128, kv_c1_w+64*128, 0, kv_c1_b+64, O,  64, 0,
                                                         stK+2, 0, nullptr, nullptr, nullptr, 0, 0.f);

        // ---- q chain (reuses H1 after kv c1 consumed it) ----
        conv1x1_v4<64,8,false><<<dim3(256,nb,2), blk, 0, stream>>>(xb, 64, q_w, 0, nullptr, Q1, 64, 0,
                                                        nullptr, 0, nullptr, nullptr, nullptr, 0, 0.f);
        dwconv_v2<5,1><<<gdw, blk, 0, stream>>>(Q1, 64, 0, q_c0_w, q_c0_b, 0, Q2, 64, 0);
        dwconv_v2<3,3><<<gdw, blk, 0, stream>>>(Q2, 64, 0, q_cs_w, q_cs_b, 0, Q1, 64, 0);
        conv1x1_v4<64,8,false><<<dim3(256,nb,2), blk, 0, stream>>>(Q1, 64, q_c1_w, 0, q_c1_b, Q2, 64, 0,
                                                        stQ, -1, nullptr, nullptr, nullptr, 0, 0.f);

        // ---- attention: GN+leaky fused into q/k staging; sumsq accumulated there ----
        attn_dot_v3<<<dim3(128,4,nb), blk, 0, stream>>>(Q2, H2, stQ, stK,
                                                        q_gn_g, q_gn_b, kv_gn_g, kv_gn_b,
                                                        arw, ssq, ssk);
        attn_softmax_v2<<<dim3(4,nb), blk, 0, stream>>>(arw, ssq, ssk, temp, atn);
        build_m_v2<<<dim3(nb), blk, 0, stream>>>(atn, proj_w, Mb);

        // ---- out = M[b] @ leaky(GN(v)), in-place on d_out; GN fused on input rows ----
        // keep 16 ch/wave + single z so every block reads all its pixels before any write
        conv1x1_v4<64,16,true><<<dim3(256,nb,1), blk, 0, stream>>>(O, 64, Mw + b0*4096, 4096, nullptr,
                                                       (float*)d_out + (size_t)b0*64*HW, 64, 0,
                                                       nullptr, 0, stK+2, kv_gn_g, kv_gn_b, 64, 64.f*HW);
    }
}

// Round 2
// 1039.542 us; speedup vs baseline: 1.3839x; 1.3839x over previous
//
#include <hip/hip_runtime.h>

#define HW 65536
#define IMG 256

__device__ __forceinline__ float hsum4(float4 v) { return v.x + v.y + v.z + v.w; }
__device__ __forceinline__ float lrelu(float v) { return v >= 0.f ? v : 0.2f * v; }

// ---------------- 1x1 conv (v5) ----------------
// NW waves (4 or 8), each wave owns 16 out-channels (co0 = wv*16), 64 px-quads per block.
// Inner loop identical to the proven v3 pattern (plain loads, unroll 4, 16 FMA4/load).
// DUAL: CIT=128 split across two input tensors (ci<64 from in, ci>=64 from in2) so the
// merged 128->128 conv can read the two 64-ch halves written by the fused dw kernels.
// stats: gsel==-1 -> group = co0>=32 ; gsel==-2 -> group = co0>=64 ; else group 0.
// GNIN: apply per-input-channel GN affine + leaky-relu while reading (single group).
template<int CIT, int NW, bool GNIN, bool DUAL>
__global__ __launch_bounds__(NW*64)
void conv1x1_v5(const float* __restrict__ in, int in_cs,
                const float* __restrict__ in2, int in2_cs,
                const float* __restrict__ w, int w_bstride,
                const float* __restrict__ bias,
                float* __restrict__ out, int out_cs, int out_coff,
                float* __restrict__ stats, int gsel,
                const float* __restrict__ gstats,
                const float* __restrict__ g_gamma, const float* __restrict__ g_beta,
                int g_coff, float g_Nf)
{
    const int b  = blockIdx.y;
    const int j  = threadIdx.x & 63;
    const int wv = __builtin_amdgcn_readfirstlane((int)(threadIdx.x >> 6));
    const int co0 = wv * 16;
    const int q0 = blockIdx.x * 64;
    const float* wb = w + (size_t)b * w_bstride;

    float gmean = 0.f, grstd = 0.f;
    if (GNIN) {
        gmean = gstats[b*4] / g_Nf;
        float var = gstats[b*4 + 1] / g_Nf - gmean * gmean;
        grstd = rsqrtf(var + 1e-5f);
    }

    float4 acc[16];
    #pragma unroll
    for (int k = 0; k < 16; ++k) {
        float bv = bias ? bias[co0 + k] : 0.f;
        acc[k] = make_float4(bv, bv, bv, bv);
    }

    const float4* in4a = (const float4*)in + (size_t)b * in_cs * (HW/4) + q0 + j;

    auto run = [&](const float4* base, const float* wrb, int n) {
        #pragma unroll 4
        for (int ci = 0; ci < n; ++ci) {
            float4 x = base[(size_t)ci * (HW/4)];
            if (GNIN) {
                float A = g_gamma[g_coff + ci] * grstd;
                float B = g_beta[g_coff + ci] - gmean * A;
                x.x = lrelu(fmaf(x.x, A, B));
                x.y = lrelu(fmaf(x.y, A, B));
                x.z = lrelu(fmaf(x.z, A, B));
                x.w = lrelu(fmaf(x.w, A, B));
            }
            const float* wr = wrb + ci;
            #pragma unroll
            for (int k = 0; k < 16; ++k) {
                float wk = wr[(size_t)(co0 + k) * CIT];
                acc[k].x = fmaf(wk, x.x, acc[k].x);
                acc[k].y = fmaf(wk, x.y, acc[k].y);
                acc[k].z = fmaf(wk, x.z, acc[k].z);
                acc[k].w = fmaf(wk, x.w, acc[k].w);
            }
        }
    };

    if (DUAL) {
        const float4* in4b = (const float4*)in2 + (size_t)b * in2_cs * (HW/4) + q0 + j;
        run(in4a, wb, 64);
        run(in4b, wb + 64, 64);   // global ci = 64 + local ci
    } else {
        run(in4a, wb, CIT);
    }

    if (!GNIN && stats) {
        float s = 0.f, ss = 0.f;
        #pragma unroll
        for (int k = 0; k < 16; ++k) {
            s  += acc[k].x + acc[k].y + acc[k].z + acc[k].w;
            ss += acc[k].x*acc[k].x + acc[k].y*acc[k].y
                + acc[k].z*acc[k].z + acc[k].w*acc[k].w;
        }
        #pragma unroll
        for (int o = 32; o; o >>= 1) { s += __shfl_down(s, o, 64); ss += __shfl_down(ss, o, 64); }
        if (j == 0) {
            int g = 0;
            if (gsel == -1) g = (co0 >= 32) ? 1 : 0;
            else if (gsel == -2) g = (co0 >= 64) ? 1 : 0;
            float* st = stats + (size_t)b*4 + g*2;
            atomicAdd(st,     s);
            atomicAdd(st + 1, ss);
        }
    }

    float4* out4 = (float4*)out + ((size_t)b * out_cs + out_coff) * (HW/4) + q0 + j;
    #pragma unroll
    for (int k = 0; k < 16; ++k)
        out4[(size_t)(co0 + k) * (HW/4)] = acc[k];
}

// ---------------- fused depthwise 5x5(pad2) -> 3x3(dil3,pad3), per channel ----------------
// Eliminates the intermediate tensor round-trip (write+read of the 5x5 output).
// Tile 32x64 output per block; 5x5 output staged in LDS with a 3-px halo for the dilated 3x3.
// grid: (4, 8, nb*64), block 256. 64 channels per dispatch via in_coff/w_coff.
__global__ __launch_bounds__(256)
void dwfused(const float* __restrict__ in, int in_cs, int in_coff,
             const float* __restrict__ w5, const float* __restrict__ b5, int w5_coff,
             const float* __restrict__ w3, const float* __restrict__ b3, int w3_coff,
             float* __restrict__ out, int out_cs, int out_coff)
{
    constexpr int TH = 32, TW = 64;
    constexpr int IN_H = TH + 10, IN_W = TW + 10;    // halo 5 = 3 (dil3 reach) + 2 (5x5 reach)
    constexpr int MID_H = TH + 6, MID_W = TW + 6;    // 5x5 output with 3-px halo
    constexpr int IN_RS = IN_W + 2;                  // 76
    constexpr int MID_RS = MID_W + 2;                // 72
    __shared__ float Xs[IN_H * IN_RS];               // 12.8 KiB
    __shared__ float Ms[MID_H * MID_RS];             // 10.9 KiB
    const int z = blockIdx.z;
    const int c = z & 63, b = z >> 6;
    const int x0 = blockIdx.x * TW, y0 = blockIdx.y * TH;
    const float* ip = in + ((size_t)b*in_cs + in_coff + c) * HW;

    float wk5[25];
    #pragma unroll
    for (int i = 0; i < 25; ++i) wk5[i] = w5[(size_t)(w5_coff + c)*25 + i];
    const float bv5 = b5[w5_coff + c];
    float wk3[9];
    #pragma unroll
    for (int i = 0; i < 9; ++i) wk3[i] = w3[(size_t)(w3_coff + c)*9 + i];
    const float bv3 = b3[w3_coff + c];

    // stage input tile (origin y0-5, x0-5), zero-padded
    for (int idx = threadIdx.x; idx < IN_H*IN_W; idx += 256) {
        int ly = idx / IN_W, lx = idx - ly*IN_W;
        int gy = y0 + ly - 5, gx = x0 + lx - 5;
        float v = 0.f;
        if (gy >= 0 && gy < IMG && gx >= 0 && gx < IMG)
            v = ip[gy*IMG + gx];
        Xs[ly*IN_RS + lx] = v;
    }
    __syncthreads();

    // 5x5 output incl. 3-px halo (origin y0-3, x0-3); zero outside image (conv pad semantics)
    for (int idx = threadIdx.x; idx < MID_H*MID_W; idx += 256) {
        int my = idx / MID_W, mx = idx - my*MID_W;
        int gy = y0 + my - 3, gx = x0 + mx - 3;
        float v = 0.f;
        if (gy >= 0 && gy < IMG && gx >= 0 && gx < IMG) {
            v = bv5;
            #pragma unroll
            for (int ky = 0; ky < 5; ++ky) {
                const float* xr = &Xs[(my + ky)*IN_RS + mx];
                #pragma unroll
                for (int kx = 0; kx < 5; ++kx)
                    v = fmaf(wk5[ky*5 + kx], xr[kx], v);
            }
        }
        Ms[my*MID_RS + mx] = v;
    }
    __syncthreads();

    // dilated 3x3 on the staged 5x5 output
    const int qx = (threadIdx.x & 15) * 4;
    const int ly0 = threadIdx.x >> 4;
    float* op = out + ((size_t)b*out_cs + out_coff + c) * HW;
    #pragma unroll
    for (int r = 0; r < 2; ++r) {
        const int oy = ly0 + r*16;
        float o0 = bv3, o1 = bv3, o2 = bv3, o3 = bv3;
        #pragma unroll
        for (int kt = 0; kt < 3; ++kt) {
            const float* mr = &Ms[(oy + 3*kt)*MID_RS + qx];
            #pragma unroll
            for (int kx = 0; kx < 3; ++kx) {
                float wv_ = wk3[kt*3 + kx];
                o0 = fmaf(wv_, mr[3*kx + 0], o0);
                o1 = fmaf(wv_, mr[3*kx + 1], o1);
                o2 = fmaf(wv_, mr[3*kx + 2], o2);
                o3 = fmaf(wv_, mr[3*kx + 3], o3);
            }
        }
        *(float4*)(op + (size_t)(y0 + oy)*IMG + x0 + qx) = make_float4(o0, o1, o2, o3);
    }
}

// ---------------- attention raw dots, with GN+leaky fused on q,k + post-act sumsq ----------------
// grid: (128, 4, nb), block 256. k tensor has stride k_cs (k lives in a 128-ch buffer).
__global__ __launch_bounds__(256)
void attn_dot_v4(const float* __restrict__ q, const float* __restrict__ k, int k_cs,
                 const float* __restrict__ stQ, const float* __restrict__ stK,
                 const float* __restrict__ qg, const float* __restrict__ qb,
                 const float* __restrict__ kg, const float* __restrict__ kb,
                 float* __restrict__ attn_raw,
                 float* __restrict__ ssq, float* __restrict__ ssk)
{
    __shared__ float4 qs[2048], ks[2048];   // 32 KiB each
    __shared__ float sred[512];
    const int h = blockIdx.y, b = blockIdx.z;
    const int t0 = blockIdx.x * 128;
    const int cc = threadIdx.x & 15;
    const int ch = h*16 + cc;               // channel index within the 64-ch tensor

    const int gq = (ch >= 32) ? 1 : 0;
    float mq = stQ[b*4 + gq*2] / (32.f * HW);
    float vq = stQ[b*4 + gq*2 + 1] / (32.f * HW) - mq*mq;
    const float Aq = qg[ch] * rsqrtf(vq + 1e-5f);
    const float Bq = qb[ch] - mq * Aq;
    float mk = stK[b*4] / (64.f * HW);
    float vk = stK[b*4 + 1] / (64.f * HW) - mk*mk;
    const float Ak = kg[ch] * rsqrtf(vk + 1e-5f);
    const float Bk = kb[ch] - mk * Ak;

    const float4* q4 = (const float4*)q + ((size_t)b*64   + ch) * (HW/4) + t0;
    const float4* k4 = (const float4*)k + ((size_t)b*k_cs + ch) * (HW/4) + t0;
    float sq_acc = 0.f, sk_acc = 0.f;
    #pragma unroll
    for (int s = 0; s < 8; ++s) {
        int t = (threadIdx.x >> 4) + s*16;
        float4 v = q4[t];
        v.x = lrelu(fmaf(v.x, Aq, Bq)); v.y = lrelu(fmaf(v.y, Aq, Bq));
        v.z = lrelu(fmaf(v.z, Aq, Bq)); v.w = lrelu(fmaf(v.w, Aq, Bq));
        sq_acc += v.x*v.x + v.y*v.y + v.z*v.z + v.w*v.w;
        qs[t*16 + cc] = v;
        float4 u = k4[t];
        u.x = lrelu(fmaf(u.x, Ak, Bk)); u.y = lrelu(fmaf(u.y, Ak, Bk));
        u.z = lrelu(fmaf(u.z, Ak, Bk)); u.w = lrelu(fmaf(u.w, Ak, Bk));
        sk_acc += u.x*u.x + u.y*u.y + u.z*u.z + u.w*u.w;
        ks[t*16 + cc] = u;
    }
    sred[threadIdx.x]       = sq_acc;
    sred[256 + threadIdx.x] = sk_acc;
    __syncthreads();

    const int p   = threadIdx.x & 63;
    const int sub = threadIdx.x >> 6;
    const int c0 = (p >> 3) << 1, d0 = (p & 7) << 1;
    float4 a00 = make_float4(0,0,0,0), a01 = a00, a10 = a00, a11 = a00;
    #pragma unroll
    for (int i = 0; i < 32; ++i) {
        int t = sub*32 + i;
        float4 qa = qs[t*16 + c0], qb_ = qs[t*16 + c0 + 1];
        float4 ka = ks[t*16 + d0], kb_ = ks[t*16 + d0 + 1];
        a00.x = fmaf(qa.x, ka.x, a00.x); a00.y = fmaf(qa.y, ka.y, a00.y);
        a00.z = fmaf(qa.z, ka.z, a00.z); a00.w = fmaf(qa.w, ka.w, a00.w);
        a01.x = fmaf(qa.x, kb_.x, a01.x); a01.y = fmaf(qa.y, kb_.y, a01.y);
        a01.z = fmaf(qa.z, kb_.z, a01.z); a01.w = fmaf(qa.w, kb_.w, a01.w);
        a10.x = fmaf(qb_.x, ka.x, a10.x); a10.y = fmaf(qb_.y, ka.y, a10.y);
        a10.z = fmaf(qb_.z, ka.z, a10.z); a10.w = fmaf(qb_.w, ka.w, a10.w);
        a11.x = fmaf(qb_.x, kb_.x, a11.x); a11.y = fmaf(qb_.y, kb_.y, a11.y);
        a11.z = fmaf(qb_.z, kb_.z, a11.z); a11.w = fmaf(qb_.w, kb_.w, a11.w);
    }
    float* ar = attn_raw + ((size_t)b*4 + h) * 256;
    atomicAdd(&ar[(c0  )*16 + d0  ], hsum4(a00));
    atomicAdd(&ar[(c0  )*16 + d0+1], hsum4(a01));
    atomicAdd(&ar[(c0+1)*16 + d0  ], hsum4(a10));
    atomicAdd(&ar[(c0+1)*16 + d0+1], hsum4(a11));

    if (threadIdx.x < 16) {
        float s = 0.f;
        #pragma unroll
        for (int jj = 0; jj < 16; ++jj) s += sred[threadIdx.x + 16*jj];
        atomicAdd(&ssq[b*64 + h*16 + threadIdx.x], s);
    } else if (threadIdx.x < 32) {
        const int c2 = threadIdx.x - 16;
        float s = 0.f;
        #pragma unroll
        for (int jj = 0; jj < 16; ++jj) s += sred[256 + c2 + 16*jj];
        atomicAdd(&ssk[b*64 + h*16 + c2], s);
    }
}

// ---------------- softmax with l2-norm scaling + temperature ----------------
__global__ __launch_bounds__(256)
void attn_softmax_v2(const float* __restrict__ attn_raw,
                     const float* __restrict__ ssq, const float* __restrict__ ssk,
                     const float* __restrict__ temp, float* __restrict__ attn)
{
    const int h = blockIdx.x, b = blockIdx.y;
    const int c = threadIdx.x >> 4, d = threadIdx.x & 15;
    const float nq = fmaxf(sqrtf(ssq[b*64 + h*16 + c]), 1e-12f);
    const float nk = fmaxf(sqrtf(ssk[b*64 + h*16 + d]), 1e-12f);
    float logit = attn_raw[((size_t)b*4 + h)*256 + c*16 + d] / (nq * nk) * temp[h];
    float m = logit;
    #pragma unroll
    for (int o = 8; o; o >>= 1) m = fmaxf(m, __shfl_xor(m, o, 16));
    float e = expf(logit - m);
    float s = e;
    #pragma unroll
    for (int o = 8; o; o >>= 1) s += __shfl_xor(s, o, 16);
    attn[((size_t)b*4 + h)*256 + c*16 + d] = e / s;
}

// ---------------- M[b] = proj . blockdiag(attn[b]) ----------------
__global__ __launch_bounds__(256)
void build_m_v2(const float* __restrict__ attn, const float* __restrict__ proj_w,
                float* __restrict__ M)
{
    const int b = blockIdx.x;
    for (int i = threadIdx.x; i < 4096; i += 256) {
        int co = i >> 6, ci = i & 63;
        int h = ci >> 4, d = ci & 15;
        float s = 0.f;
        #pragma unroll
        for (int cc = 0; cc < 16; ++cc)
            s += proj_w[co*64 + h*16 + cc] * attn[((size_t)b*4 + h)*256 + cc*16 + d];
        M[(size_t)b*4096 + i] = s;
    }
}

extern "C" void kernel_launch(void* const* d_in, const int* in_sizes, int n_in,
                              void* d_out, int out_size, void* d_ws, size_t ws_size,
                              hipStream_t stream)
{
    const float* x       = (const float*)d_in[0];
    const float* y       = (const float*)d_in[1];
    const float* kv_w    = (const float*)d_in[2];
    const float* q_w     = (const float*)d_in[3];
    const float* proj_w  = (const float*)d_in[4];
    const float* kv_c0_w = (const float*)d_in[5];
    const float* kv_c0_b = (const float*)d_in[6];
    const float* kv_cs_w = (const float*)d_in[7];
    const float* kv_cs_b = (const float*)d_in[8];
    const float* kv_c1_w = (const float*)d_in[9];
    const float* kv_c1_b = (const float*)d_in[10];
    const float* kv_gn_g = (const float*)d_in[11];
    const float* kv_gn_b = (const float*)d_in[12];
    const float* q_c0_w  = (const float*)d_in[13];
    const float* q_c0_b  = (const float*)d_in[14];
    const float* q_cs_w  = (const float*)d_in[15];
    const float* q_cs_b  = (const float*)d_in[16];
    const float* q_c1_w  = (const float*)d_in[17];
    const float* q_c1_b  = (const float*)d_in[18];
    const float* q_gn_g  = (const float*)d_in[19];
    const float* q_gn_b  = (const float*)d_in[20];
    const float* temp    = (const float*)d_in[21];

    float* ws       = (float*)d_ws;
    float* statsKV  = ws;            // 4/batch  -> 16
    float* statsQ   = ws + 16;
    float* sumsq_k  = ws + 32;       // 64/batch -> 256
    float* sumsq_q  = ws + 288;
    float* attn_raw = ws + 544;      // 1024/batch -> 4096
    float* attn     = ws + 4640;
    float* Mw       = ws + 8736;     // 4096/batch -> 16384 (end 25120)
    float* big      = (float*)((char*)d_ws + 131072);

    // per-batch big-buffer need: H1 = 128*HW, H2 = 64*HW floats (48 MiB); v-half/q use d_out
    const size_t perb_bytes = (size_t)192 * HW * 4;
    int nb = 1;
    if      (ws_size >= 131072 + 4*perb_bytes) nb = 4;
    else if (ws_size >= 131072 + 2*perb_bytes) nb = 2;

    hipMemsetAsync(d_ws, 0, 102400, stream);
    dim3 blk(256);

    for (int b0 = 0; b0 < 4; b0 += nb) {
        const float* xb = x + (size_t)b0*64*HW;
        const float* yb = y + (size_t)b0*64*HW;
        float* H1 = big;                          // nb*128*HW : kvpre out, later k(0:64)|v_raw(64:128)
        float* H2 = big + (size_t)nb*128*HW;      // nb*64*HW  : dw-out k-half, later q mid
        float* O  = (float*)d_out + (size_t)b0*64*HW;   // nb*64*HW : dw-out v-half, later q
        float* stK = statsKV + b0*4;
        float* stQ = statsQ  + b0*4;
        float* ssk = sumsq_k + b0*64;
        float* ssq = sumsq_q + b0*64;
        float* arw = attn_raw + b0*1024;
        float* atn = attn     + b0*1024;
        float* Mb  = Mw       + b0*4096;

        dim3 gdwf(4, 8, nb*64);
        dim3 gc(256, nb);

        // ---- kv chain ----
        // y -> H1 (128 ch), single 512-thread dispatch: y read once per block, 8 waves share via L1
        conv1x1_v5<64,8,false,false><<<gc, dim3(512), 0, stream>>>(
            yb, 64, nullptr, 0, kv_w, 0, nullptr, H1, 128, 0,
            nullptr, 0, nullptr, nullptr, nullptr, 0, 0.f);
        // fused dw5x5 + dw3x3d3: H1 -> {H2 (ch 0..63), O (ch 64..127)} — no intermediate tensor
        dwfused<<<gdwf, blk, 0, stream>>>(H1, 128, 0,  kv_c0_w, kv_c0_b, 0,  kv_cs_w, kv_cs_b, 0,  H2, 64, 0);
        dwfused<<<gdwf, blk, 0, stream>>>(H1, 128, 64, kv_c0_w, kv_c0_b, 64, kv_cs_w, kv_cs_b, 64, O,  64, 0);
        // merged 128->128 1x1 (dual input), k -> H1[0:64], v_raw -> H1[64:128], fused GN stats
        conv1x1_v5<128,8,false,true><<<gc, dim3(512), 0, stream>>>(
            H2, 64, O, 64, kv_c1_w, 0, kv_c1_b, H1, 128, 0,
            stK, -2, nullptr, nullptr, nullptr, 0, 0.f);

        // ---- q chain (uses O and H2; H1 holds k/v) ----
        conv1x1_v5<64,4,false,false><<<gc, blk, 0, stream>>>(
            xb, 64, nullptr, 0, q_w, 0, nullptr, O, 64, 0,
            nullptr, 0, nullptr, nullptr, nullptr, 0, 0.f);
        dwfused<<<gdwf, blk, 0, stream>>>(O, 64, 0, q_c0_w, q_c0_b, 0, q_cs_w, q_cs_b, 0, H2, 64, 0);
        conv1x1_v5<64,4,false,false><<<gc, blk, 0, stream>>>(
            H2, 64, nullptr, 0, q_c1_w, 0, q_c1_b, O, 64, 0,
            stQ, -1, nullptr, nullptr, nullptr, 0, 0.f);

        // ---- attention ----
        attn_dot_v4<<<dim3(128,4,nb), blk, 0, stream>>>(O, H1, 128, stQ, stK,
                                                        q_gn_g, q_gn_b, kv_gn_g, kv_gn_b,
                                                        arw, ssq, ssk);
        attn_softmax_v2<<<dim3(4,nb), blk, 0, stream>>>(arw, ssq, ssk, temp, atn);
        build_m_v2<<<dim3(nb), blk, 0, stream>>>(atn, proj_w, Mb);

        // ---- out = M[b] @ leaky(GN(v_raw)), v_raw = H1[64:128]; writes d_out (not in-place) ----
        conv1x1_v5<64,4,true,false><<<gc, blk, 0, stream>>>(
            H1 + (size_t)64*HW, 128, nullptr, 0, Mw + b0*4096, 4096, nullptr,
            (float*)d_out + (size_t)b0*64*HW, 64, 0,
            nullptr, 0, stK+2, kv_gn_g, kv_gn_b, 64, 64.f*HW);
    }
}